// Round 1
// baseline (1478.097 us; speedup 1.0000x reference)
//
#include <hip/hip_runtime.h>
#include <hip/hip_cooperative_groups.h>

namespace cg = cooperative_groups;

#define N_IMG  100000
#define C_CLS  1000
#define CP     1024    // padded class count
#define DIM    512     // att_dim == img_dim
#define HPROJ  256     // H
#define CAP    512     // per-class bucket capacity
#define GRID_B 512     // cooperative grid size (co-resident: 2 blocks/CU)

struct Params {
    const float* image_feats;   // [100000, 512]
    const float* attributes;    // [1000, 512]
    const float* att_g;         // [512, 256]
    const float* att_h;         // [512, 256]
    const int*   labels;        // [100000]
    const int*   tpl;           // [1000]
    float*       out;           // [1000, 512]
    float*       protos;        // [1000, 512]
    float*       XnT;           // [256][1024]
    float*       WT;            // [1024][1024]
    float*       Ppart;         // [2][1024][256]
    float*       Qpart;         // [2][1024][512]
    int*         cnt;           // [1024] zeroed
    float*       rsum1;         // [1024] zeroed
    float*       rsum2;         // [1024] zeroed
    int*         perm;          // [1000*512]
};

// One shared-memory block reused by every phase (max member = score: 38.25 KB)
union SMem {
    struct { int list[CAP]; float4 acc[128]; } g;                       // gather
    struct { float At[64][34]; float Wt[64][36]; } p;                   // proj
    struct { float Xi[64][68]; float Xj[64][68]; float rp[64][17]; } s; // score
    struct { float Wt[64][68]; float Vt[64][68]; } m;                   // mm
    struct { float red[4][4]; float srn[4]; } n;                        // norm
};

// ---------------------------------------------------------------------------
// proj: P[kz] = A_eff @ Wm partial GEMM. 512 blocks (8 x 32 x 2), 32x32 tile,
// 2x2/thread, split-K x2. A_eff = A0 or (Q0+Q1)/rsum (fused combine).
// ---------------------------------------------------------------------------
__device__ __forceinline__ void proj_phase(SMem& sm, int b, int t,
    const float* __restrict__ A0, const float* __restrict__ Qp,
    const float* __restrict__ rsum, const float* __restrict__ Wm,
    float* __restrict__ Pout)
{
    const int j0 = (b & 7) * 32;
    const int i0 = ((b >> 3) & 31) * 32;
    const int kz = b >> 8;
    const int tx = t & 15, ty = t >> 4;
    float a00 = 0.f, a01 = 0.f, a10 = 0.f, a11 = 0.f;
    for (int ch = 0; ch < 4; ++ch) {
        const int kb = kz * 256 + ch * 64;
        __syncthreads();
        for (int l = t; l < 512; l += 256) {
            const int r = l >> 4, f = l & 15;
            const int row = min(i0 + r, C_CLS - 1);
            float4 v;
            if (A0) {
                v = *(const float4*)(A0 + (size_t)row * DIM + kb + 4 * f);
            } else {
                const float4 q0 = *(const float4*)(Qp + (size_t)row * DIM + kb + 4 * f);
                const float4 q1 = *(const float4*)(Qp + (size_t)CP * DIM + (size_t)row * DIM + kb + 4 * f);
                const float rs = 1.0f / rsum[row];
                v.x = (q0.x + q1.x) * rs; v.y = (q0.y + q1.y) * rs;
                v.z = (q0.z + q1.z) * rs; v.w = (q0.w + q1.w) * rs;
            }
            sm.p.At[4*f+0][r] = v.x; sm.p.At[4*f+1][r] = v.y;
            sm.p.At[4*f+2][r] = v.z; sm.p.At[4*f+3][r] = v.w;
        }
        for (int l = t; l < 512; l += 256) {
            const int kk = l >> 3, f = l & 7;
            *(float4*)&sm.p.Wt[kk][4*f] =
                *(const float4*)(Wm + (size_t)(kb + kk) * HPROJ + j0 + 4 * f);
        }
        __syncthreads();
#pragma unroll 8
        for (int kk = 0; kk < 64; ++kk) {
            const float2 a = *(const float2*)&sm.p.At[kk][2 * ty];
            const float2 w = *(const float2*)&sm.p.Wt[kk][2 * tx];
            a00 = fmaf(a.x, w.x, a00); a01 = fmaf(a.x, w.y, a01);
            a10 = fmaf(a.y, w.x, a10); a11 = fmaf(a.y, w.y, a11);
        }
    }
    float* dst = Pout + (size_t)kz * CP * HPROJ;
    const int i = i0 + 2 * ty;
    *(float2*)(dst + (size_t)i * HPROJ + j0 + 2 * tx) = make_float2(a00, a01);
    *(float2*)(dst + (size_t)(i + 1) * HPROJ + j0 + 2 * tx) = make_float2(a10, a11);
}

// ---------------------------------------------------------------------------
// norm: row-normalize (P0+P1), write transposed XnT[256][1024]. 250 blocks.
// ---------------------------------------------------------------------------
__device__ __forceinline__ void norm_phase(SMem& sm, int b, int t,
    const float* __restrict__ Pin, float* __restrict__ XnT)
{
    if (b >= 250) return;
    const int i0 = b * 4;
    float x[4], ss[4];
#pragma unroll
    for (int u = 0; u < 4; ++u) {
        x[u] = Pin[(size_t)(i0 + u) * HPROJ + t]
             + Pin[(size_t)CP * HPROJ + (size_t)(i0 + u) * HPROJ + t];
        ss[u] = x[u] * x[u];
    }
#pragma unroll
    for (int off = 32; off > 0; off >>= 1)
#pragma unroll
        for (int u = 0; u < 4; ++u) ss[u] += __shfl_down(ss[u], off);
    if ((t & 63) == 0) {
        const int wv = t >> 6;
#pragma unroll
        for (int u = 0; u < 4; ++u) sm.n.red[u][wv] = ss[u];
    }
    __syncthreads();
    if (t < 4) sm.n.srn[t] = rsqrtf(sm.n.red[t][0] + sm.n.red[t][1] +
                                    sm.n.red[t][2] + sm.n.red[t][3]);
    __syncthreads();
    float4 tv;
    tv.x = x[0] * sm.n.srn[0]; tv.y = x[1] * sm.n.srn[1];
    tv.z = x[2] * sm.n.srn[2]; tv.w = x[3] * sm.n.srn[3];
    *(float4*)(XnT + (size_t)t * CP + i0) = tv;
}

// ---------------------------------------------------------------------------
// score: WT[j][i] = maskexp(cos_ij) + fused row-sum atomics. 256 blocks.
// ---------------------------------------------------------------------------
__device__ __forceinline__ void score_phase(SMem& sm, int b, int t,
    const float* __restrict__ XnT, float* __restrict__ WT,
    float* __restrict__ rsum)
{
    if (b >= 256) return;
    const int j0 = (b & 15) * 64;
    const int i0 = (b >> 4) * 64;
    const int tx = t & 15, ty = t >> 4;
    float acc[4][4] = {};
    for (int ch = 0; ch < 4; ++ch) {
        const int kb = ch * 64;
        __syncthreads();
        for (int l = t; l < 1024; l += 256) {
            const int kk = l >> 4, f = l & 15;
            const float* src = XnT + (size_t)(kb + kk) * CP;
            *(float4*)&sm.s.Xi[kk][4 * f] = *(const float4*)(src + i0 + 4 * f);
            *(float4*)&sm.s.Xj[kk][4 * f] = *(const float4*)(src + j0 + 4 * f);
        }
        __syncthreads();
#pragma unroll 8
        for (int kk = 0; kk < 64; ++kk) {
            const float4 a = *(const float4*)&sm.s.Xi[kk][4 * ty];
            const float4 bb = *(const float4*)&sm.s.Xj[kk][4 * tx];
            const float av[4] = {a.x, a.y, a.z, a.w};
            const float bv[4] = {bb.x, bb.y, bb.z, bb.w};
#pragma unroll
            for (int u = 0; u < 4; ++u)
#pragma unroll
                for (int v = 0; v < 4; ++v)
                    acc[u][v] = fmaf(av[u], bv[v], acc[u][v]);
        }
    }
    float rp[4] = {0.f, 0.f, 0.f, 0.f};
#pragma unroll
    for (int v = 0; v < 4; ++v) {
        const int j = j0 + 4 * tx + v;
        const bool jv = (j < C_CLS);
        float4 o;
#pragma unroll
        for (int u = 0; u < 4; ++u) {
            const float d = acc[u][v];
            const float w = (jv && d > 0.5f) ? __expf(10.f * d) : 0.f;
            ((float*)&o)[u] = w;
            rp[u] += w;
        }
        *(float4*)(WT + (size_t)j * CP + i0 + 4 * ty) = o;
    }
#pragma unroll
    for (int u = 0; u < 4; ++u) sm.s.rp[4 * ty + u][tx] = rp[u];
    __syncthreads();
    if (t < 64) {
        float s = 0.f;
#pragma unroll 16
        for (int k = 0; k < 16; ++k) s += sm.s.rp[t][k];
        const int i = i0 + t;
        if (i < C_CLS) atomicAdd(&rsum[i], s);
    }
}

// ---------------------------------------------------------------------------
// mm: Q[kz] = W @ V partial GEMM from WT. 256 blocks (8 x 16 x 2), split-K x2.
// ---------------------------------------------------------------------------
__device__ __forceinline__ void mm_phase(SMem& sm, int b, int t,
    const float* __restrict__ WT, const float* __restrict__ V,
    const int* __restrict__ vidx, float* __restrict__ Q)
{
    if (b >= 256) return;
    const int c0 = (b & 7) * 64;
    const int i0 = ((b >> 3) & 15) * 64;
    const int kz = (b >> 7) & 1;
    const int tx = t & 15, ty = t >> 4;
    float acc[4][4] = {};
    for (int ch = 0; ch < 8; ++ch) {
        const int kb = kz * 512 + ch * 64;
        __syncthreads();
        for (int l = t; l < 1024; l += 256) {
            const int kk = l >> 4, f = l & 15;
            *(float4*)&sm.m.Wt[kk][4 * f] =
                *(const float4*)(WT + (size_t)(kb + kk) * CP + i0 + 4 * f);
            const int jc = min(kb + kk, C_CLS - 1);
            const int vr = vidx ? vidx[jc] : jc;
            *(float4*)&sm.m.Vt[kk][4 * f] =
                *(const float4*)(V + (size_t)vr * DIM + c0 + 4 * f);
        }
        __syncthreads();
#pragma unroll 8
        for (int kk = 0; kk < 64; ++kk) {
            const float4 w = *(const float4*)&sm.m.Wt[kk][4 * ty];
            const float4 v = *(const float4*)&sm.m.Vt[kk][4 * tx];
            const float wv[4] = {w.x, w.y, w.z, w.w};
            const float vv[4] = {v.x, v.y, v.z, v.w};
#pragma unroll
            for (int u = 0; u < 4; ++u)
#pragma unroll
                for (int cv = 0; cv < 4; ++cv)
                    acc[u][cv] = fmaf(wv[u], vv[cv], acc[u][cv]);
        }
    }
    float* dst = Q + (size_t)kz * CP * DIM;
#pragma unroll
    for (int u = 0; u < 4; ++u) {
        const int i = i0 + 4 * ty + u;
        float4 o = {acc[u][0], acc[u][1], acc[u][2], acc[u][3]};
        *(float4*)(dst + (size_t)i * DIM + c0 + 4 * tx) = o;
    }
}

// ---------------------------------------------------------------------------
// The whole pipeline in ONE cooperative kernel: 11 phases, 10 grid syncs.
// ---------------------------------------------------------------------------
__global__ __launch_bounds__(256, 2) void mega_kernel(Params P)
{
    __shared__ SMem sm;
    cg::grid_group grid = cg::this_grid();
    const int b = blockIdx.x;
    const int t = threadIdx.x;

    // ---- P0: fill (labels -> per-class row lists); cnt pre-zeroed ----------
    {
        const int i = b * 256 + t;
        if (i < N_IMG) {
            const int c = P.labels[i];
            const int p = atomicAdd(&P.cnt[c], 1);
            if (p < CAP) P.perm[c * CAP + p] = i;
        }
    }
    __threadfence();
    grid.sync();

    // ---- P1: gather (per-class mean -> protos), grid-stride over classes ---
    for (int c = b; c < C_CLS; c += GRID_B) {
        __syncthreads();   // smem reuse across class iterations
        const int n = min(P.cnt[c], CAP);
        for (int m = t; m < n; m += 256) sm.g.list[m] = P.perm[c * CAP + m];
        __syncthreads();
        const int half = t >> 7;
        const int tc   = t & 127;
        float4 a0 = {0,0,0,0}, a1 = {0,0,0,0}, a2 = {0,0,0,0}, a3 = {0,0,0,0};
        int m = half;
        for (; m + 6 < n; m += 8) {
            const float4 v0 = *(const float4*)(P.image_feats + (size_t)sm.g.list[m]     * DIM + 4 * tc);
            const float4 v1 = *(const float4*)(P.image_feats + (size_t)sm.g.list[m + 2] * DIM + 4 * tc);
            const float4 v2 = *(const float4*)(P.image_feats + (size_t)sm.g.list[m + 4] * DIM + 4 * tc);
            const float4 v3 = *(const float4*)(P.image_feats + (size_t)sm.g.list[m + 6] * DIM + 4 * tc);
            a0.x += v0.x; a0.y += v0.y; a0.z += v0.z; a0.w += v0.w;
            a1.x += v1.x; a1.y += v1.y; a1.z += v1.z; a1.w += v1.w;
            a2.x += v2.x; a2.y += v2.y; a2.z += v2.z; a2.w += v2.w;
            a3.x += v3.x; a3.y += v3.y; a3.z += v3.z; a3.w += v3.w;
        }
        for (; m < n; m += 2) {
            const float4 v0 = *(const float4*)(P.image_feats + (size_t)sm.g.list[m] * DIM + 4 * tc);
            a0.x += v0.x; a0.y += v0.y; a0.z += v0.z; a0.w += v0.w;
        }
        a0.x += a1.x + a2.x + a3.x; a0.y += a1.y + a2.y + a3.y;
        a0.z += a1.z + a2.z + a3.z; a0.w += a1.w + a2.w + a3.w;
        if (half) sm.g.acc[tc] = a0;
        __syncthreads();
        if (!half) {
            const float4 o = sm.g.acc[tc];
            const float inv = 1.0f / (float)n;
            float4 r;
            r.x = (a0.x + o.x) * inv; r.y = (a0.y + o.y) * inv;
            r.z = (a0.z + o.z) * inv; r.w = (a0.w + o.w) * inv;
            *(float4*)(P.protos + (size_t)c * DIM + 4 * tc) = r;
        }
    }
    __threadfence();
    grid.sync();

    // ---- stage 1: enc path --------------------------------------------------
    proj_phase(sm, b, t, P.attributes, nullptr, nullptr, P.att_h, P.Ppart);
    __threadfence(); grid.sync();
    norm_phase(sm, b, t, P.Ppart, P.XnT);
    __threadfence(); grid.sync();
    score_phase(sm, b, t, P.XnT, P.WT, P.rsum1);
    __threadfence(); grid.sync();
    mm_phase(sm, b, t, P.WT, P.attributes, nullptr, P.Qpart);
    __threadfence(); grid.sync();

    // ---- stage 2: attention path (combine of stage-1 fused into proj) ------
    proj_phase(sm, b, t, nullptr, P.Qpart, P.rsum1, P.att_g, P.Ppart);
    __threadfence(); grid.sync();
    norm_phase(sm, b, t, P.Ppart, P.XnT);
    __threadfence(); grid.sync();
    score_phase(sm, b, t, P.XnT, P.WT, P.rsum2);
    __threadfence(); grid.sync();
    mm_phase(sm, b, t, P.WT, P.protos, P.tpl, P.Qpart);
    __threadfence(); grid.sync();

    // ---- P10: combine -> out ------------------------------------------------
    {
        const int idx = b * 256 + t;   // f4 index
        if (idx < C_CLS * DIM / 4) {
            const int i = idx >> 7;
            const float4 a = *(const float4*)(P.Qpart + (size_t)4 * idx);
            const float4 q = *(const float4*)(P.Qpart + (size_t)CP * DIM + (size_t)4 * idx);
            const float s = 1.0f / P.rsum2[i];
            float4 o;
            o.x = s * (a.x + q.x); o.y = s * (a.y + q.y);
            o.z = s * (a.z + q.z); o.w = s * (a.w + q.w);
            *(float4*)(P.out + (size_t)4 * idx) = o;
        }
    }
}

// ---------------------------------------------------------------------------
extern "C" void kernel_launch(void* const* d_in, const int* in_sizes, int n_in,
                              void* d_out, int out_size, void* d_ws, size_t ws_size,
                              hipStream_t stream) {
    Params p;
    p.image_feats = (const float*)d_in[0];
    p.attributes  = (const float*)d_in[1];
    p.att_g       = (const float*)d_in[2];
    p.att_h       = (const float*)d_in[3];
    p.labels      = (const int*)d_in[4];
    p.tpl         = (const int*)d_in[5];
    p.out         = (float*)d_out;

    float* ws = (float*)d_ws;
    p.protos = ws;                          // 512000
    p.XnT    = p.protos + 512000;           // 262144
    p.WT     = p.XnT + 262144;              // 1048576
    p.Ppart  = p.WT + 1048576;              // 524288
    p.Qpart  = p.Ppart + 524288;            // 1048576
    p.cnt    = (int*)(p.Qpart + 1048576);   // 1024  (zero-block start)
    p.rsum1  = (float*)(p.cnt + 1024);      // 1024
    p.rsum2  = p.rsum1 + 1024;              // 1024
    p.perm   = (int*)(p.rsum2 + 1024);      // 512000

    hipMemsetAsync(p.cnt, 0, 3 * 1024 * sizeof(int), stream);
    void* args[] = { &p };
    hipLaunchCooperativeKernel((const void*)mega_kernel,
                               dim3(GRID_B), dim3(256), args, 0, stream);
}

// Round 2
// 422.819 us; speedup vs baseline: 3.4958x; 3.4958x over previous
//
#include <hip/hip_runtime.h>

#define N_IMG 100000
#define C_CLS 1000
#define CP    1024    // padded class count
#define DIM   512     // att_dim == img_dim
#define HPROJ 256     // H
#define CAP   512     // per-class bucket capacity
#define FILL_BLKS 391 // ceil(100000/256)

// ---------------------------------------------------------------------------
// Shared-memory unions
// ---------------------------------------------------------------------------
struct PSm {                 // proj (256-thread kernels)
    float At[64][34];
    float Wt[64][36];
};
union BSm {                  // 512-thread fused kernels
    struct { float Xi[64][68]; float Xj[64][68]; float rp[64][17]; } s;  // score
    struct { float Wt[64][68]; float Vt[64][68]; } m;                    // mm
    struct { int list[CAP]; float4 acc[3][128]; } g;                     // gather
};

// ---------------------------------------------------------------------------
// proj: P[kz] = A_eff @ Wm partial GEMM. 512 blocks, 32x32 tile, 2x2/thread,
// split-K x2. A_eff = A0 or (Q0+Q1)/rsum (fused combine of prev stage).
// ---------------------------------------------------------------------------
__device__ __forceinline__ void proj_dev(PSm& sm, int b, int t,
    const float* __restrict__ A0, const float* __restrict__ Qp,
    const float* __restrict__ rsum, const float* __restrict__ Wm,
    float* __restrict__ Pout)
{
    const int j0 = (b & 7) * 32;
    const int i0 = ((b >> 3) & 31) * 32;
    const int kz = b >> 8;
    const int tx = t & 15, ty = t >> 4;
    float a00 = 0.f, a01 = 0.f, a10 = 0.f, a11 = 0.f;
    for (int ch = 0; ch < 4; ++ch) {
        const int kb = kz * 256 + ch * 64;
        __syncthreads();
        for (int l = t; l < 512; l += 256) {
            const int r = l >> 4, f = l & 15;
            const int row = min(i0 + r, C_CLS - 1);
            float4 v;
            if (A0) {
                v = *(const float4*)(A0 + (size_t)row * DIM + kb + 4 * f);
            } else {
                const float4 q0 = *(const float4*)(Qp + (size_t)row * DIM + kb + 4 * f);
                const float4 q1 = *(const float4*)(Qp + (size_t)CP * DIM + (size_t)row * DIM + kb + 4 * f);
                const float rs = 1.0f / rsum[row];
                v.x = (q0.x + q1.x) * rs; v.y = (q0.y + q1.y) * rs;
                v.z = (q0.z + q1.z) * rs; v.w = (q0.w + q1.w) * rs;
            }
            sm.At[4*f+0][r] = v.x; sm.At[4*f+1][r] = v.y;
            sm.At[4*f+2][r] = v.z; sm.At[4*f+3][r] = v.w;
        }
        for (int l = t; l < 512; l += 256) {
            const int kk = l >> 3, f = l & 7;
            *(float4*)&sm.Wt[kk][4*f] =
                *(const float4*)(Wm + (size_t)(kb + kk) * HPROJ + j0 + 4 * f);
        }
        __syncthreads();
#pragma unroll 8
        for (int kk = 0; kk < 64; ++kk) {
            const float2 a = *(const float2*)&sm.At[kk][2 * ty];
            const float2 w = *(const float2*)&sm.Wt[kk][2 * tx];
            a00 = fmaf(a.x, w.x, a00); a01 = fmaf(a.x, w.y, a01);
            a10 = fmaf(a.y, w.x, a10); a11 = fmaf(a.y, w.y, a11);
        }
    }
    float* dst = Pout + (size_t)kz * CP * HPROJ;
    const int i = i0 + 2 * ty;
    *(float2*)(dst + (size_t)i * HPROJ + j0 + 2 * tx) = make_float2(a00, a01);
    *(float2*)(dst + (size_t)(i + 1) * HPROJ + j0 + 2 * tx) = make_float2(a10, a11);
}

// ---------------------------------------------------------------------------
// gather (512-thread): per-class mean of image_feats rows -> protos[c].
// ---------------------------------------------------------------------------
__device__ __forceinline__ void gather_dev(BSm& sm, int c, int t,
    const float* __restrict__ image_feats, const int* __restrict__ cnt,
    const int* __restrict__ perm, float* __restrict__ protos)
{
    const int n = min(cnt[c], CAP);
    for (int m = t; m < n; m += 512) sm.g.list[m] = perm[c * CAP + m];
    __syncthreads();
    const int q  = t >> 7;     // row-stream quarter 0..3
    const int tc = t & 127;    // float4 column group
    float4 a0 = {0,0,0,0}, a1 = {0,0,0,0};
    int m = q;
    for (; m + 4 < n; m += 8) {
        const float4 v0 = *(const float4*)(image_feats + (size_t)sm.g.list[m]     * DIM + 4 * tc);
        const float4 v1 = *(const float4*)(image_feats + (size_t)sm.g.list[m + 4] * DIM + 4 * tc);
        a0.x += v0.x; a0.y += v0.y; a0.z += v0.z; a0.w += v0.w;
        a1.x += v1.x; a1.y += v1.y; a1.z += v1.z; a1.w += v1.w;
    }
    for (; m < n; m += 4) {
        const float4 v0 = *(const float4*)(image_feats + (size_t)sm.g.list[m] * DIM + 4 * tc);
        a0.x += v0.x; a0.y += v0.y; a0.z += v0.z; a0.w += v0.w;
    }
    a0.x += a1.x; a0.y += a1.y; a0.z += a1.z; a0.w += a1.w;
    if (q) sm.g.acc[q - 1][tc] = a0;
    __syncthreads();
    if (q == 0) {
        const float4 o1 = sm.g.acc[0][tc];
        const float4 o2 = sm.g.acc[1][tc];
        const float4 o3 = sm.g.acc[2][tc];
        const float inv = 1.0f / (float)n;
        float4 r;
        r.x = (a0.x + o1.x + o2.x + o3.x) * inv;
        r.y = (a0.y + o1.y + o2.y + o3.y) * inv;
        r.z = (a0.z + o1.z + o2.z + o3.z) * inv;
        r.w = (a0.w + o1.w + o2.w + o3.w) * inv;
        *(float4*)(protos + (size_t)c * DIM + 4 * tc) = r;
    }
}

// ---------------------------------------------------------------------------
// score (512-thread): WT[j][i] = maskexp(cos_ij) + fused row-sum atomics.
// 256 blocks, 64x64 tile, 2x4/thread.
// ---------------------------------------------------------------------------
__device__ __forceinline__ void score_dev(BSm& sm, int b, int t,
    const float* __restrict__ XnT, float* __restrict__ WT,
    float* __restrict__ rsum)
{
    const int j0 = (b & 15) * 64;
    const int i0 = (b >> 4) * 64;
    const int tx = t & 15, ty = t >> 4;   // ty 0..31
    float acc[2][4] = {};
    for (int ch = 0; ch < 4; ++ch) {
        const int kb = ch * 64;
        __syncthreads();
        for (int l = t; l < 1024; l += 512) {
            const int kk = l >> 4, f = l & 15;
            const float* src = XnT + (size_t)(kb + kk) * CP;
            *(float4*)&sm.s.Xi[kk][4 * f] = *(const float4*)(src + i0 + 4 * f);
            *(float4*)&sm.s.Xj[kk][4 * f] = *(const float4*)(src + j0 + 4 * f);
        }
        __syncthreads();
#pragma unroll 8
        for (int kk = 0; kk < 64; ++kk) {
            const float2 a  = *(const float2*)&sm.s.Xi[kk][2 * ty];
            const float4 bb = *(const float4*)&sm.s.Xj[kk][4 * tx];
            const float av[2] = {a.x, a.y};
            const float bv[4] = {bb.x, bb.y, bb.z, bb.w};
#pragma unroll
            for (int u = 0; u < 2; ++u)
#pragma unroll
                for (int v = 0; v < 4; ++v)
                    acc[u][v] = fmaf(av[u], bv[v], acc[u][v]);
        }
    }
    float rp[2] = {0.f, 0.f};
#pragma unroll
    for (int v = 0; v < 4; ++v) {
        const int j = j0 + 4 * tx + v;
        const bool jv = (j < C_CLS);
        float2 o;
#pragma unroll
        for (int u = 0; u < 2; ++u) {
            const float d = acc[u][v];
            const float w = (jv && d > 0.5f) ? __expf(10.f * d) : 0.f;
            ((float*)&o)[u] = w;
            rp[u] += w;
        }
        *(float2*)(WT + (size_t)j * CP + i0 + 2 * ty) = o;
    }
    sm.s.rp[2 * ty + 0][tx] = rp[0];
    sm.s.rp[2 * ty + 1][tx] = rp[1];
    __syncthreads();
    if (t < 64) {
        float s = 0.f;
#pragma unroll 16
        for (int k = 0; k < 16; ++k) s += sm.s.rp[t][k];
        const int i = i0 + t;
        if (i < C_CLS) atomicAdd(&rsum[i], s);
    }
}

// ---------------------------------------------------------------------------
// mm (512-thread): Q[kz] = W @ V partial GEMM from WT. 256 blocks (8x16x2),
// 64x64 tile, 2x4/thread, split-K x2 over K=1024.
// ---------------------------------------------------------------------------
__device__ __forceinline__ void mm_dev(BSm& sm, int b, int t,
    const float* __restrict__ WT, const float* __restrict__ V,
    const int* __restrict__ vidx, float* __restrict__ Q)
{
    const int c0 = (b & 7) * 64;
    const int i0 = ((b >> 3) & 15) * 64;
    const int kz = b >> 7;
    const int tx = t & 15, ty = t >> 4;   // ty 0..31
    float acc[2][4] = {};
    for (int ch = 0; ch < 8; ++ch) {
        const int kb = kz * 512 + ch * 64;
        __syncthreads();
        for (int l = t; l < 1024; l += 512) {
            const int kk = l >> 4, f = l & 15;
            *(float4*)&sm.m.Wt[kk][4 * f] =
                *(const float4*)(WT + (size_t)(kb + kk) * CP + i0 + 4 * f);
            const int jc = min(kb + kk, C_CLS - 1);
            const int vr = vidx ? vidx[jc] : jc;
            *(float4*)&sm.m.Vt[kk][4 * f] =
                *(const float4*)(V + (size_t)vr * DIM + c0 + 4 * f);
        }
        __syncthreads();
#pragma unroll 8
        for (int kk = 0; kk < 64; ++kk) {
            const float2 w = *(const float2*)&sm.m.Wt[kk][2 * ty];
            const float4 v = *(const float4*)&sm.m.Vt[kk][4 * tx];
            const float wv[2] = {w.x, w.y};
            const float vv[4] = {v.x, v.y, v.z, v.w};
#pragma unroll
            for (int u = 0; u < 2; ++u)
#pragma unroll
                for (int cv = 0; cv < 4; ++cv)
                    acc[u][cv] = fmaf(wv[u], vv[cv], acc[u][cv]);
        }
    }
    float* dst = Q + (size_t)kz * CP * DIM;
#pragma unroll
    for (int u = 0; u < 2; ++u) {
        const int i = i0 + 2 * ty + u;
        float4 o = {acc[u][0], acc[u][1], acc[u][2], acc[u][3]};
        *(float4*)(dst + (size_t)i * DIM + c0 + 4 * tx) = o;
    }
}

// ---------------------------------------------------------------------------
// K1: fill ∥ proj1. grid 903 @ 256.
// ---------------------------------------------------------------------------
__global__ __launch_bounds__(256) void k_fill_proj(
    const int* __restrict__ labels, int* __restrict__ cnt, int* __restrict__ perm,
    const float* __restrict__ A0, const float* __restrict__ Wm,
    float* __restrict__ Pout)
{
    __shared__ PSm sm;
    const int b = blockIdx.x, t = threadIdx.x;
    if (b < FILL_BLKS) {
        const int i = b * 256 + t;
        if (i < N_IMG) {
            const int c = labels[i];
            const int p = atomicAdd(&cnt[c], 1);
            if (p < CAP) perm[c * CAP + p] = i;
        }
    } else {
        proj_dev(sm, b - FILL_BLKS, t, A0, nullptr, nullptr, Wm, Pout);
    }
}

// ---------------------------------------------------------------------------
// K5: proj2 (fused combine of stage-1). grid 512 @ 256.
// ---------------------------------------------------------------------------
__global__ __launch_bounds__(256) void k_proj(
    const float* __restrict__ Qp, const float* __restrict__ rsum,
    const float* __restrict__ Wm, float* __restrict__ Pout)
{
    __shared__ PSm sm;
    proj_dev(sm, blockIdx.x, threadIdx.x, nullptr, Qp, rsum, Wm, Pout);
}

// ---------------------------------------------------------------------------
// norm: row-normalize (P0+P1), write transposed XnT[256][1024]. 250 @ 256.
// ---------------------------------------------------------------------------
__global__ __launch_bounds__(256) void norm_kernel(
    const float* __restrict__ P, float* __restrict__ XnT)
{
    __shared__ float red[4][4];
    __shared__ float srn[4];
    const int i0 = blockIdx.x * 4;
    const int t  = threadIdx.x;
    float x[4], ss[4];
#pragma unroll
    for (int u = 0; u < 4; ++u) {
        x[u] = P[(size_t)(i0 + u) * HPROJ + t]
             + P[(size_t)CP * HPROJ + (size_t)(i0 + u) * HPROJ + t];
        ss[u] = x[u] * x[u];
    }
#pragma unroll
    for (int off = 32; off > 0; off >>= 1)
#pragma unroll
        for (int u = 0; u < 4; ++u) ss[u] += __shfl_down(ss[u], off);
    if ((t & 63) == 0) {
        const int wv = t >> 6;
#pragma unroll
        for (int u = 0; u < 4; ++u) red[u][wv] = ss[u];
    }
    __syncthreads();
    if (t < 4) srn[t] = rsqrtf(red[t][0] + red[t][1] + red[t][2] + red[t][3]);
    __syncthreads();
    float4 tv;
    tv.x = x[0] * srn[0]; tv.y = x[1] * srn[1];
    tv.z = x[2] * srn[2]; tv.w = x[3] * srn[3];
    *(float4*)(XnT + (size_t)t * CP + i0) = tv;
}

// ---------------------------------------------------------------------------
// K3/K7: score ∥ gather-half. grid 256(+cnum) @ 512.
// ---------------------------------------------------------------------------
__global__ __launch_bounds__(512) void k_score_gather(
    const float* __restrict__ XnT, float* __restrict__ WT, float* __restrict__ rsum,
    const float* __restrict__ image_feats, const int* __restrict__ cnt,
    const int* __restrict__ perm, float* __restrict__ protos, int cbase)
{
    __shared__ BSm sm;
    const int b = blockIdx.x, t = threadIdx.x;
    if (b < 256) score_dev(sm, b, t, XnT, WT, rsum);
    else         gather_dev(sm, cbase + (b - 256), t, image_feats, cnt, perm, protos);
}

// ---------------------------------------------------------------------------
// K4/K8: mm ∥ gather-half. grid 256(+cnum) @ 512.
// ---------------------------------------------------------------------------
__global__ __launch_bounds__(512) void k_mm_gather(
    const float* __restrict__ WT, const float* __restrict__ V,
    const int* __restrict__ vidx, float* __restrict__ Q,
    const float* __restrict__ image_feats, const int* __restrict__ cnt,
    const int* __restrict__ perm, float* __restrict__ protos, int cbase)
{
    __shared__ BSm sm;
    const int b = blockIdx.x, t = threadIdx.x;
    if (b < 256) mm_dev(sm, b, t, WT, V, vidx, Q);
    else         gather_dev(sm, cbase + (b - 256), t, image_feats, cnt, perm, protos);
}

// ---------------------------------------------------------------------------
// K9: Out[i,c] = (Q0[i,c]+Q1[i,c]) / rsum[i]. grid 500 @ 256.
// ---------------------------------------------------------------------------
__global__ __launch_bounds__(256) void combine_kernel(
    const float* __restrict__ Q, const float* __restrict__ rsum,
    float* __restrict__ Out)
{
    const int idx = blockIdx.x * 256 + threadIdx.x;   // f4 index
    if (idx < C_CLS * DIM / 4) {
        const int i = idx >> 7;
        const float4 a = *(const float4*)(Q + (size_t)4 * idx);
        const float4 b = *(const float4*)(Q + (size_t)CP * DIM + (size_t)4 * idx);
        const float s = 1.0f / rsum[i];
        float4 o;
        o.x = s * (a.x + b.x); o.y = s * (a.y + b.y);
        o.z = s * (a.z + b.z); o.w = s * (a.w + b.w);
        *(float4*)(Out + (size_t)4 * idx) = o;
    }
}

// ---------------------------------------------------------------------------
extern "C" void kernel_launch(void* const* d_in, const int* in_sizes, int n_in,
                              void* d_out, int out_size, void* d_ws, size_t ws_size,
                              hipStream_t stream) {
    const float* image_feats = (const float*)d_in[0];  // [100000, 512]
    const float* attributes  = (const float*)d_in[1];  // [1000, 512]
    const float* att_g       = (const float*)d_in[2];  // [512, 256]
    const float* att_h       = (const float*)d_in[3];  // [512, 256]
    const int*   labels      = (const int*)d_in[4];    // [100000]
    const int*   tpl         = (const int*)d_in[5];    // [1000]
    float* out = (float*)d_out;                        // [1000, 512]

    float* ws     = (float*)d_ws;
    float* protos = ws;                       // 512000
    float* XnT    = protos + 512000;          // 262144
    float* WT     = XnT + 262144;             // 1048576
    float* Ppart  = WT + 1048576;             // 524288
    float* Qpart  = Ppart + 524288;           // 1048576
    int*   cnt    = (int*)(Qpart + 1048576);  // 1024  (zero-block start)
    float* rsum1  = (float*)(cnt + 1024);     // 1024
    float* rsum2  = rsum1 + 1024;             // 1024
    int*   perm   = (int*)(rsum2 + 1024);     // 512000

    hipMemsetAsync(cnt, 0, 3 * 1024 * sizeof(int), stream);

    // K1: fill ∥ proj1 (attributes @ att_h -> Ppart)
    k_fill_proj<<<FILL_BLKS + 512, 256, 0, stream>>>(
        labels, cnt, perm, attributes, att_h, Ppart);
    // K2: norm1
    norm_kernel<<<250, 256, 0, stream>>>(Ppart, XnT);
    // K3: score1 ∥ gather classes [0,500)
    k_score_gather<<<256 + 500, 512, 0, stream>>>(
        XnT, WT, rsum1, image_feats, cnt, perm, protos, 0);
    // K4: mm1 ∥ gather classes [500,1000)
    k_mm_gather<<<256 + 500, 512, 0, stream>>>(
        WT, attributes, nullptr, Qpart, image_feats, cnt, perm, protos, 500);
    // K5: proj2 (combine(Qpart)/rsum1 @ att_g -> Ppart)
    k_proj<<<512, 256, 0, stream>>>(Qpart, rsum1, att_g, Ppart);
    // K6: norm2
    norm_kernel<<<250, 256, 0, stream>>>(Ppart, XnT);
    // K7: score2 (no gather blocks)
    k_score_gather<<<256, 512, 0, stream>>>(
        XnT, WT, rsum2, image_feats, cnt, perm, protos, 0);
    // K8: mm2 (V = protos via tpl)
    k_mm_gather<<<256, 512, 0, stream>>>(
        WT, protos, tpl, Qpart, image_feats, cnt, perm, protos, 0);
    // K9: combine -> out
    combine_kernel<<<500, 256, 0, stream>>>(Qpart, rsum2, out);
}